// Round 1
// baseline (1917.597 us; speedup 1.0000x reference)
//
#include <hip/hip_runtime.h>
#include <hip/hip_bf16.h>

// Problem constants (MPNet self-attention)
#define B_  2
#define S_  2048
#define D_  1024
#define H_  16
#define HD_ 64
#define M_  (B_ * S_)   // 4096 rows

// ---------------------------------------------------------------------------
// GEMM: out = A[M,K] @ W[K,N] + bias[N]
// out_mode 0: row-major [M,N]
// out_mode 1: QKV scatter to [B,H,S,HD] with m=b*S+s, n=h*HD+d
// Tile: 128x128, BK=16, 256 threads, 8x8 per thread (split 4+4, 64 apart)
// ---------------------------------------------------------------------------
#define GBM 128
#define GBN 128
#define GBK 16

__global__ __launch_bounds__(256) void gemm_bias(
    const float* __restrict__ A, const float* __restrict__ W,
    const float* __restrict__ bias, float* __restrict__ out,
    int M, int N, int K, int out_mode)
{
    __shared__ float As[GBK][GBM + 4];   // transposed: As[k][m], row 132 floats (528B, 16B-aligned)
    __shared__ float Bs[GBK][GBN + 4];

    const int tid = threadIdx.x;
    const int bm = blockIdx.x * GBM;
    const int bn = blockIdx.y * GBN;
    const int ty = tid >> 4;   // 0..15
    const int tx = tid & 15;   // 0..15

    float acc[8][8];
#pragma unroll
    for (int i = 0; i < 8; ++i)
#pragma unroll
        for (int j = 0; j < 8; ++j) acc[i][j] = 0.f;

    for (int k0 = 0; k0 < K; k0 += GBK) {
        // A tile: 128 rows x 16 k, float4 along k, store transposed
#pragma unroll
        for (int p = 0; p < 2; ++p) {
            const int idx = tid + p * 256;        // 0..511
            const int row = idx >> 2;             // 0..127
            const int c4  = idx & 3;              // 0..3
            const float4 v = *(const float4*)&A[(size_t)(bm + row) * K + k0 + c4 * 4];
            As[c4 * 4 + 0][row] = v.x;
            As[c4 * 4 + 1][row] = v.y;
            As[c4 * 4 + 2][row] = v.z;
            As[c4 * 4 + 3][row] = v.w;
        }
        // B tile: 16 rows x 128 cols, float4 along n
#pragma unroll
        for (int p = 0; p < 2; ++p) {
            const int idx  = tid + p * 256;       // 0..511
            const int krow = idx >> 5;            // 0..15
            const int c4   = idx & 31;            // 0..31
            const float4 v = *(const float4*)&W[(size_t)(k0 + krow) * N + bn + c4 * 4];
            *(float4*)&Bs[krow][c4 * 4] = v;
        }
        __syncthreads();

#pragma unroll
        for (int k = 0; k < GBK; ++k) {
            float ra[8], rb[8];
            *(float4*)&ra[0] = *(const float4*)&As[k][ty * 4];
            *(float4*)&ra[4] = *(const float4*)&As[k][64 + ty * 4];
            *(float4*)&rb[0] = *(const float4*)&Bs[k][tx * 4];
            *(float4*)&rb[4] = *(const float4*)&Bs[k][64 + tx * 4];
#pragma unroll
            for (int i = 0; i < 8; ++i)
#pragma unroll
                for (int j = 0; j < 8; ++j)
                    acc[i][j] = fmaf(ra[i], rb[j], acc[i][j]);
        }
        __syncthreads();
    }

    // epilogue
#pragma unroll
    for (int i = 0; i < 8; ++i) {
        const int m = bm + ty * 4 + (i & 3) + (i >> 2) * 64;
#pragma unroll
        for (int jh = 0; jh < 2; ++jh) {
            const int n = bn + tx * 4 + jh * 64;
            const float4 bv = *(const float4*)&bias[n];
            float4 o;
            o.x = acc[i][jh * 4 + 0] + bv.x;
            o.y = acc[i][jh * 4 + 1] + bv.y;
            o.z = acc[i][jh * 4 + 2] + bv.z;
            o.w = acc[i][jh * 4 + 3] + bv.w;
            if (out_mode == 0) {
                *(float4*)&out[(size_t)m * N + n] = o;
            } else {
                const int bb = m >> 11;          // m / S_
                const int ss = m & (S_ - 1);
                const int hh = n >> 6;           // n / HD_
                const int dd = n & (HD_ - 1);
                *(float4*)&out[(((size_t)bb * H_ + hh) * S_ + ss) * HD_ + dd] = o;
            }
        }
    }
}

// ---------------------------------------------------------------------------
// Flash-style attention, fp32.
// Block = 256 threads, handles one (b, h, 64-row q-tile); loops 64-wide k-tiles.
// Qt/Kt in LDS transposed [d][row] stride 68 (16B-aligned rows, <=2-way banks),
// Vs row-major [k][d] stride 68, P in Ss [q][k] stride 65.
// grid.x = qt*2 + b so both batches of the same bias rows dispatch adjacently.
// ---------------------------------------------------------------------------
#define TQ 64
#define TK 64
#define QT_LD 68
#define VS_LD 68
#define SS_LD 65

__global__ __launch_bounds__(256) void attn_kernel(
    const float* __restrict__ Q,     // [B,H,S,HD]
    const float* __restrict__ Km,    // [B,H,S,HD]
    const float* __restrict__ Vm,    // [B,H,S,HD]
    const float* __restrict__ pbias, // [H,S,S]
    const float* __restrict__ mask,  // [B,S]
    float* __restrict__ ctx)         // [B,S,D]
{
    __shared__ float Qt[64 * QT_LD];
    __shared__ float Kt[64 * QT_LD];
    __shared__ float Vs[64 * VS_LD];
    __shared__ float Ss[64 * SS_LD];
    __shared__ float m_s[64], l_s[64], alpha_s[64];

    const int tid = threadIdx.x;
    const int qt = blockIdx.x >> 1;
    const int b  = blockIdx.x & 1;
    const int h  = blockIdx.y;
    const int q0 = qt * TQ;

    const size_t bh = (size_t)b * H_ + h;
    const float* Qbase = Q  + bh * S_ * HD_;
    const float* Kbase = Km + bh * S_ * HD_;
    const float* Vbase = Vm + bh * S_ * HD_;

    const int ty = tid >> 4, tx = tid & 15;   // score mapping: q=ty*4+i, k=tx*4+j
    const int qo = tid >> 2, dg = tid & 3;    // PV mapping: O[qo][dg*16 .. +15]

    // load Q tile transposed
#pragma unroll
    for (int p = 0; p < 4; ++p) {
        const int idx = tid + p * 256;   // 0..1023
        const int row = idx >> 4;        // 0..63
        const int c4  = idx & 15;        // 0..15
        const float4 v = *(const float4*)&Qbase[(size_t)(q0 + row) * HD_ + c4 * 4];
        Qt[(c4 * 4 + 0) * QT_LD + row] = v.x;
        Qt[(c4 * 4 + 1) * QT_LD + row] = v.y;
        Qt[(c4 * 4 + 2) * QT_LD + row] = v.z;
        Qt[(c4 * 4 + 3) * QT_LD + row] = v.w;
    }
    if (tid < 64) { m_s[tid] = -1e30f; l_s[tid] = 0.f; }

    float O[16];
#pragma unroll
    for (int i = 0; i < 16; ++i) O[i] = 0.f;

    for (int kt = 0; kt < S_ / TK; ++kt) {
        __syncthreads();   // previous iteration's consumers done (also covers Q/init at kt=0)

        // load K tile transposed + V tile row-major
#pragma unroll
        for (int p = 0; p < 4; ++p) {
            const int idx = tid + p * 256;
            const int row = idx >> 4;
            const int c4  = idx & 15;
            const float4 v = *(const float4*)&Kbase[(size_t)(kt * TK + row) * HD_ + c4 * 4];
            Kt[(c4 * 4 + 0) * QT_LD + row] = v.x;
            Kt[(c4 * 4 + 1) * QT_LD + row] = v.y;
            Kt[(c4 * 4 + 2) * QT_LD + row] = v.z;
            Kt[(c4 * 4 + 3) * QT_LD + row] = v.w;
            const float4 w = *(const float4*)&Vbase[(size_t)(kt * TK + row) * HD_ + c4 * 4];
            *(float4*)&Vs[row * VS_LD + c4 * 4] = w;
        }
        __syncthreads();

        // scores: 4q x 4k per thread
        float acc[4][4];
#pragma unroll
        for (int i = 0; i < 4; ++i)
#pragma unroll
            for (int j = 0; j < 4; ++j) acc[i][j] = 0.f;

#pragma unroll 4
        for (int d = 0; d < 64; ++d) {
            float rq[4], rk[4];
            *(float4*)rq = *(const float4*)&Qt[d * QT_LD + ty * 4];
            *(float4*)rk = *(const float4*)&Kt[d * QT_LD + tx * 4];
#pragma unroll
            for (int i = 0; i < 4; ++i)
#pragma unroll
                for (int j = 0; j < 4; ++j)
                    acc[i][j] = fmaf(rq[i], rk[j], acc[i][j]);
        }

        // scale + position bias + additive mask
        const float4 mk4 = *(const float4*)&mask[(size_t)b * S_ + kt * TK + tx * 4];
        const float mk[4] = {mk4.x, mk4.y, mk4.z, mk4.w};
        float sc[4][4];
#pragma unroll
        for (int i = 0; i < 4; ++i) {
            const int q = ty * 4 + i;
            const float4 pb4 = *(const float4*)&pbias[((size_t)h * S_ + (q0 + q)) * S_ + kt * TK + tx * 4];
            sc[i][0] = fmaf(acc[i][0], 0.125f, pb4.x + mk[0]);
            sc[i][1] = fmaf(acc[i][1], 0.125f, pb4.y + mk[1]);
            sc[i][2] = fmaf(acc[i][2], 0.125f, pb4.z + mk[2]);
            sc[i][3] = fmaf(acc[i][3], 0.125f, pb4.w + mk[3]);
        }

        // online softmax per q-row (16 tx-lanes per row, same wave)
#pragma unroll
        for (int i = 0; i < 4; ++i) {
            const int q = ty * 4 + i;
            float rmax = fmaxf(fmaxf(sc[i][0], sc[i][1]), fmaxf(sc[i][2], sc[i][3]));
#pragma unroll
            for (int off = 1; off < 16; off <<= 1)
                rmax = fmaxf(rmax, __shfl_xor(rmax, off, 64));
            const float mo = m_s[q];
            const float lo = l_s[q];
            const float mn = fmaxf(mo, rmax);
            const float al = __expf(mo - mn);
            float lsum = 0.f;
#pragma unroll
            for (int j = 0; j < 4; ++j) {
                const float p = __expf(sc[i][j] - mn);
                Ss[q * SS_LD + tx * 4 + j] = p;
                lsum += p;
            }
#pragma unroll
            for (int off = 1; off < 16; off <<= 1)
                lsum += __shfl_xor(lsum, off, 64);
            if (tx == 0) {
                m_s[q] = mn;
                l_s[q] = fmaf(lo, al, lsum);
                alpha_s[q] = al;
            }
        }
        __syncthreads();   // Ss + alpha ready

        // PV accumulate: O[qo][dg*16..+15]
        {
            const float al = alpha_s[qo];
#pragma unroll
            for (int i = 0; i < 16; ++i) O[i] *= al;
#pragma unroll 2
            for (int k = 0; k < TK; ++k) {
                const float p = Ss[qo * SS_LD + k];
                float rv[16];
                *(float4*)&rv[0]  = *(const float4*)&Vs[k * VS_LD + dg * 16 + 0];
                *(float4*)&rv[4]  = *(const float4*)&Vs[k * VS_LD + dg * 16 + 4];
                *(float4*)&rv[8]  = *(const float4*)&Vs[k * VS_LD + dg * 16 + 8];
                *(float4*)&rv[12] = *(const float4*)&Vs[k * VS_LD + dg * 16 + 12];
#pragma unroll
                for (int i = 0; i < 16; ++i) O[i] = fmaf(p, rv[i], O[i]);
            }
        }
    }

    // finalize: divide by l, write ctx[b][q0+qo][h*64 + dg*16 + i]
    const float inv = 1.f / l_s[qo];
    float res[16];
#pragma unroll
    for (int i = 0; i < 16; ++i) res[i] = O[i] * inv;
    float* obase = ctx + ((size_t)b * S_ + q0 + qo) * D_ + h * HD_ + dg * 16;
    *(float4*)&obase[0]  = *(float4*)&res[0];
    *(float4*)&obase[4]  = *(float4*)&res[4];
    *(float4*)&obase[8]  = *(float4*)&res[8];
    *(float4*)&obase[12] = *(float4*)&res[12];
}

// ---------------------------------------------------------------------------
extern "C" void kernel_launch(void* const* d_in, const int* in_sizes, int n_in,
                              void* d_out, int out_size, void* d_ws, size_t ws_size,
                              hipStream_t stream) {
    const float* X    = (const float*)d_in[0];   // [B,S,D]
    const float* mask = (const float*)d_in[1];   // [B,S]
    const float* pb   = (const float*)d_in[2];   // [H,S,S]
    const float* Wq   = (const float*)d_in[3];
    const float* bq   = (const float*)d_in[4];
    const float* Wk   = (const float*)d_in[5];
    const float* bk   = (const float*)d_in[6];
    const float* Wv   = (const float*)d_in[7];
    const float* bv   = (const float*)d_in[8];
    const float* Wo   = (const float*)d_in[9];
    const float* bo   = (const float*)d_in[10];
    float* out = (float*)d_out;

    // workspace: Q, K, V in [B,H,S,HD], ctx in [B,S,D] — 4 x 16 MB = 64 MB
    float* Qw = (float*)d_ws;
    float* Kw = Qw + (size_t)M_ * D_;
    float* Vw = Kw + (size_t)M_ * D_;
    float* Cw = Vw + (size_t)M_ * D_;

    dim3 ggrid(M_ / GBM, D_ / GBN);   // 32 x 8
    gemm_bias<<<ggrid, 256, 0, stream>>>(X, Wq, bq, Qw, M_, D_, D_, 1);
    gemm_bias<<<ggrid, 256, 0, stream>>>(X, Wk, bk, Kw, M_, D_, D_, 1);
    gemm_bias<<<ggrid, 256, 0, stream>>>(X, Wv, bv, Vw, M_, D_, D_, 1);

    dim3 agrid((S_ / TQ) * B_, H_);   // 64 x 16, b folded into x for bias locality
    attn_kernel<<<agrid, 256, 0, stream>>>(Qw, Kw, Vw, pb, mask, Cw);

    gemm_bias<<<ggrid, 256, 0, stream>>>(Cw, Wo, bo, out, M_, D_, D_, 0);
}

// Round 2
// 529.332 us; speedup vs baseline: 3.6227x; 3.6227x over previous
//
#include <hip/hip_runtime.h>
#include <hip/hip_bf16.h>

#define B_  2
#define S_  2048
#define D_  1024
#define H_  16
#define HD_ 64
#define M_  (B_ * S_)   // 4096

typedef unsigned short u16;
typedef __attribute__((ext_vector_type(8))) short short8;
typedef __attribute__((ext_vector_type(4))) float f32x4;

#define MFMA16(a, b, c) __builtin_amdgcn_mfma_f32_16x16x32_bf16(a, b, c, 0, 0, 0)

__device__ __forceinline__ u16 f2bf(float f) {
    union { float f; unsigned u; } v; v.f = f;
    unsigned r = v.u + 0x7FFFu + ((v.u >> 16) & 1u);  // RNE
    return (u16)(r >> 16);
}

__device__ __forceinline__ void gl_lds16(const void* g, void* lds) {
    __builtin_amdgcn_global_load_lds(
        (const __attribute__((address_space(1))) unsigned int*)g,
        (__attribute__((address_space(3))) unsigned int*)lds, 16, 0, 0);
}

// ---------------------------------------------------------------------------
// Pre-pass 1: fp32 -> bf16 (X)
// ---------------------------------------------------------------------------
__global__ __launch_bounds__(256) void cvt_bf16(const float* __restrict__ x,
                                                u16* __restrict__ y) {
    const int i = (blockIdx.x * 256 + threadIdx.x) * 4;
    const float4 v = *(const float4*)(x + i);
    ushort4 o;
    o.x = f2bf(v.x); o.y = f2bf(v.y); o.z = f2bf(v.z); o.w = f2bf(v.w);
    *(ushort4*)(y + i) = o;
}

// ---------------------------------------------------------------------------
// Pre-pass 2: W[K,N] fp32 -> Wt[N,K] bf16, 4 weights via blockIdx.z
// ---------------------------------------------------------------------------
__global__ __launch_bounds__(256) void wt_trans(
    const float* __restrict__ w0, const float* __restrict__ w1,
    const float* __restrict__ w2, const float* __restrict__ w3,
    u16* __restrict__ t0, u16* __restrict__ t1,
    u16* __restrict__ t2, u16* __restrict__ t3) {
    const float* W; u16* T;
    switch (blockIdx.z) {
        case 0: W = w0; T = t0; break;
        case 1: W = w1; T = t1; break;
        case 2: W = w2; T = t2; break;
        default: W = w3; T = t3; break;
    }
    __shared__ float t[32][33];
    const int tid = threadIdx.x;
    const int kt = blockIdx.x, nt = blockIdx.y;
    const int r = tid >> 3, c4 = (tid & 7) * 4;
    const float4 v = *(const float4*)&W[(size_t)(kt * 32 + r) * D_ + nt * 32 + c4];
    t[c4 + 0][r] = v.x; t[c4 + 1][r] = v.y; t[c4 + 2][r] = v.z; t[c4 + 3][r] = v.w;
    __syncthreads();
    ushort4 o;
    o.x = f2bf(t[r][c4 + 0]); o.y = f2bf(t[r][c4 + 1]);
    o.z = f2bf(t[r][c4 + 2]); o.w = f2bf(t[r][c4 + 3]);
    *(ushort4*)&T[(size_t)(nt * 32 + r) * D_ + kt * 32 + c4] = o;
}

// ---------------------------------------------------------------------------
// bf16 MFMA GEMM (m97 pattern): C[M,N] = A[M,K] @ Bt[N,K]^T + bias
// 128x128 tile, BK=32, 256 thr = 2x2 waves, each wave 64x64 (4x4 MFMA frags).
// mode 1: scatter bf16 to [B,H,S,HD];  mode 0: fp32 row-major [M,N].
// grid.z selects {Bt,bias,out} set (fused QKV).
// ---------------------------------------------------------------------------
__global__ __launch_bounds__(256) void gemm_bt_bf16(
    const u16* __restrict__ A,
    const u16* __restrict__ Bt0, const u16* __restrict__ Bt1, const u16* __restrict__ Bt2,
    const float* __restrict__ bi0, const float* __restrict__ bi1, const float* __restrict__ bi2,
    void* __restrict__ o0, void* __restrict__ o1, void* __restrict__ o2,
    int mode) {
    const u16* Bt; const float* bias; void* outp;
    switch (blockIdx.z) {
        case 0: Bt = Bt0; bias = bi0; outp = o0; break;
        case 1: Bt = Bt1; bias = bi1; outp = o1; break;
        default: Bt = Bt2; bias = bi2; outp = o2; break;
    }
    __shared__ __align__(16) char smem[16384];   // As 8K | Bs 8K

    const int tid = threadIdx.x;
    const int wave = tid >> 6, lane = tid & 63;
    const int quad = lane >> 4, l15 = lane & 15;
    const int wm = wave >> 1, wn = wave & 1;
    const int bm = blockIdx.x * 128, bn = blockIdx.y * 128;

    f32x4 acc[4][4];
#pragma unroll
    for (int i = 0; i < 4; ++i)
#pragma unroll
        for (int j = 0; j < 4; ++j) acc[i][j] = (f32x4)0.f;

    for (int k0 = 0; k0 < D_; k0 += 32) {
        __syncthreads();
#pragma unroll
        for (int i = 0; i < 2; ++i) {
            const int c = (wave * 2 + i) * 64 + lane;   // 16B chunk id 0..511
            const int row = c >> 2, e = c & 3;
            gl_lds16(A  + (size_t)(bm + row) * D_ + k0 + e * 8,
                     smem + (wave * 2 + i) * 1024);
            gl_lds16(Bt + (size_t)(bn + row) * D_ + k0 + e * 8,
                     smem + 8192 + (wave * 2 + i) * 1024);
        }
        __syncthreads();

        short8 aF[4], bF[4];
#pragma unroll
        for (int mt = 0; mt < 4; ++mt)
            aF[mt] = *(const short8*)(smem + ((wm * 64 + mt * 16 + l15) * 32 + quad * 8) * 2);
#pragma unroll
        for (int nt = 0; nt < 4; ++nt)
            bF[nt] = *(const short8*)(smem + 8192 + ((wn * 64 + nt * 16 + l15) * 32 + quad * 8) * 2);
#pragma unroll
        for (int mt = 0; mt < 4; ++mt)
#pragma unroll
            for (int nt = 0; nt < 4; ++nt)
                acc[mt][nt] = MFMA16(aF[mt], bF[nt], acc[mt][nt]);
    }

    float bv[4];
#pragma unroll
    for (int nt = 0; nt < 4; ++nt) bv[nt] = bias[bn + wn * 64 + nt * 16 + l15];

    if (mode == 1) {
        u16* ob = (u16*)outp;
#pragma unroll
        for (int mt = 0; mt < 4; ++mt)
#pragma unroll
            for (int nt = 0; nt < 4; ++nt)
#pragma unroll
                for (int r = 0; r < 4; ++r) {
                    const int m = bm + wm * 64 + mt * 16 + quad * 4 + r;
                    const int n = bn + wn * 64 + nt * 16 + l15;
                    const int bb = m >> 11, ss = m & (S_ - 1);
                    const int hh = n >> 6,  dd = n & (HD_ - 1);
                    ob[(((size_t)bb * H_ + hh) * S_ + ss) * HD_ + dd] =
                        f2bf(acc[mt][nt][r] + bv[nt]);
                }
    } else {
        float* of = (float*)outp;
#pragma unroll
        for (int mt = 0; mt < 4; ++mt)
#pragma unroll
            for (int nt = 0; nt < 4; ++nt)
#pragma unroll
                for (int r = 0; r < 4; ++r) {
                    const int m = bm + wm * 64 + mt * 16 + quad * 4 + r;
                    const int n = bn + wn * 64 + nt * 16 + l15;
                    of[(size_t)m * D_ + n] = acc[mt][nt][r] + bv[nt];
                }
    }
}

// ---------------------------------------------------------------------------
// MFMA flash attention. Block = 256 thr (4 waves), 128 q-rows (32/wave),
// k-tiles of 64. Q/K staged via global_load_lds with XOR chunk swizzle;
// V transposed into padded LDS; P round-trips wave-private LDS (C->A layout).
// ---------------------------------------------------------------------------
#define QS_OFF 0        // 128x64 bf16 = 16384 B (swizzled 16B chunks)
#define KS_OFF 16384    //  64x64 bf16 =  8192 B (swizzled)
#define VT_OFF 24576    //  [64 d][72 k] bf16 = 9216 B
#define PS_OFF 33792    //  [128 q][72 k] bf16 = 18432 B  -> total 52224
#define VT_LD 72
#define PS_LD 72

__global__ __launch_bounds__(256) void attn_mfma(
    const u16* __restrict__ Qg, const u16* __restrict__ Kg, const u16* __restrict__ Vg,
    const float* __restrict__ pb, const float* __restrict__ mask,
    u16* __restrict__ Cb) {
    __shared__ __align__(16) char smem[52224];
    u16* Vt = (u16*)(smem + VT_OFF);
    u16* Ps = (u16*)(smem + PS_OFF);

    const int tid = threadIdx.x;
    const int wave = tid >> 6, lane = tid & 63;
    const int quad = lane >> 4, l15 = lane & 15;

    const int b = blockIdx.x & 1, qblk = blockIdx.x >> 1;
    const int h = blockIdx.y;
    const int q0 = qblk * 128;

    const size_t bh = (size_t)b * H_ + h;
    const u16* Qb = Qg + bh * (S_ * HD_);
    const u16* Kb = Kg + bh * (S_ * HD_);
    const u16* Vb = Vg + bh * (S_ * HD_);

    // stage Q tile 128x64, swizzled: chunk (q,e) holds global d-chunk e^(q&7)
#pragma unroll
    for (int i = 0; i < 4; ++i) {
        const int c = (wave * 4 + i) * 64 + lane;  // 0..1023
        const int q = c >> 3, e = c & 7, dc = e ^ (q & 7);
        gl_lds16(Qb + (size_t)(q0 + q) * HD_ + dc * 8,
                 smem + QS_OFF + (wave * 4 + i) * 1024);
    }

    f32x4 O[2][4];
    float mst[2][4], lst[2][4];
#pragma unroll
    for (int t2 = 0; t2 < 2; ++t2) {
#pragma unroll
        for (int nt = 0; nt < 4; ++nt) O[t2][nt] = (f32x4)0.f;
#pragma unroll
        for (int r = 0; r < 4; ++r) { mst[t2][r] = -1e30f; lst[t2][r] = 0.f; }
    }

    for (int kt = 0; kt < S_ / 64; ++kt) {
        const int k0 = kt * 64;
        __syncthreads();   // prior consumers of Ks/Vt done (covers Q staging at kt=0)

        // stage K tile 64x64 swizzled
#pragma unroll
        for (int i = 0; i < 2; ++i) {
            const int c = (wave * 2 + i) * 64 + lane;  // 0..511
            const int q = c >> 3, e = c & 7, dc = e ^ (q & 7);
            gl_lds16(Kb + (size_t)(k0 + q) * HD_ + dc * 8,
                     smem + KS_OFF + (wave * 2 + i) * 1024);
        }
        // stage V transposed: Vt[d][k]
        {
            const int k = tid & 63, dh = tid >> 6;
#pragma unroll
            for (int p = 0; p < 2; ++p) {
                const int d0 = dh * 16 + p * 8;
                u16 tmp[8];
                *(uint4*)tmp = *(const uint4*)(Vb + (size_t)(k0 + k) * HD_ + d0);
#pragma unroll
                for (int j = 0; j < 8; ++j) Vt[(d0 + j) * VT_LD + k] = tmp[j];
            }
        }
        // bias + mask into C-layout registers (overlaps with staging)
        float mk[4], pbv[2][4][4];
#pragma unroll
        for (int nt = 0; nt < 4; ++nt) mk[nt] = mask[b * S_ + k0 + nt * 16 + l15];
#pragma unroll
        for (int t2 = 0; t2 < 2; ++t2)
#pragma unroll
            for (int r = 0; r < 4; ++r) {
                const int qg = q0 + wave * 32 + t2 * 16 + quad * 4 + r;
                const float* rowp = pb + ((size_t)h * S_ + qg) * S_ + k0;
#pragma unroll
                for (int nt = 0; nt < 4; ++nt) pbv[t2][r][nt] = rowp[nt * 16 + l15];
            }
        __syncthreads();   // staging visible

        // ---- QK^T ----
        f32x4 sc[2][4];
#pragma unroll
        for (int t2 = 0; t2 < 2; ++t2)
#pragma unroll
            for (int nt = 0; nt < 4; ++nt) sc[t2][nt] = (f32x4)0.f;

        short8 aQ[2][2];
#pragma unroll
        for (int t2 = 0; t2 < 2; ++t2)
#pragma unroll
            for (int kc = 0; kc < 2; ++kc) {
                const int q = wave * 32 + t2 * 16 + l15;
                const int dc = kc * 4 + quad;
                aQ[t2][kc] = *(const short8*)(smem + QS_OFF + (q * 8 + (dc ^ (q & 7))) * 16);
            }
#pragma unroll
        for (int nt = 0; nt < 4; ++nt)
#pragma unroll
            for (int kc = 0; kc < 2; ++kc) {
                const int kk = nt * 16 + l15;
                const int dc = kc * 4 + quad;
                const short8 bK = *(const short8*)(smem + KS_OFF + (kk * 8 + (dc ^ (kk & 7))) * 16);
                sc[0][nt] = MFMA16(aQ[0][kc], bK, sc[0][nt]);
                sc[1][nt] = MFMA16(aQ[1][kc], bK, sc[1][nt]);
            }

        // ---- online softmax (rows = quad*4+r), write P to wave-private LDS ----
#pragma unroll
        for (int t2 = 0; t2 < 2; ++t2)
#pragma unroll
            for (int r = 0; r < 4; ++r) {
                float s0 = fmaf(sc[t2][0][r], 0.125f, pbv[t2][r][0] + mk[0]);
                float s1 = fmaf(sc[t2][1][r], 0.125f, pbv[t2][r][1] + mk[1]);
                float s2 = fmaf(sc[t2][2][r], 0.125f, pbv[t2][r][2] + mk[2]);
                float s3 = fmaf(sc[t2][3][r], 0.125f, pbv[t2][r][3] + mk[3]);
                float rmax = fmaxf(fmaxf(s0, s1), fmaxf(s2, s3));
#pragma unroll
                for (int off = 1; off < 16; off <<= 1)
                    rmax = fmaxf(rmax, __shfl_xor(rmax, off, 64));
                const float mo = mst[t2][r];
                const float mn = fmaxf(mo, rmax);
                const float al = __expf(mo - mn);
                const float p0 = __expf(s0 - mn), p1 = __expf(s1 - mn);
                const float p2 = __expf(s2 - mn), p3 = __expf(s3 - mn);
                float ls = (p0 + p1) + (p2 + p3);
#pragma unroll
                for (int off = 1; off < 16; off <<= 1)
                    ls += __shfl_xor(ls, off, 64);
                mst[t2][r] = mn;
                lst[t2][r] = fmaf(lst[t2][r], al, ls);
                const int qr = wave * 32 + t2 * 16 + quad * 4 + r;
                Ps[qr * PS_LD +  0 + l15] = f2bf(p0);
                Ps[qr * PS_LD + 16 + l15] = f2bf(p1);
                Ps[qr * PS_LD + 32 + l15] = f2bf(p2);
                Ps[qr * PS_LD + 48 + l15] = f2bf(p3);
                O[t2][0][r] *= al; O[t2][1][r] *= al;
                O[t2][2][r] *= al; O[t2][3][r] *= al;
            }

        // ---- PV (A from wave-private Ps: in-wave DS ordering, no barrier) ----
        short8 aP[2][2];
#pragma unroll
        for (int t2 = 0; t2 < 2; ++t2)
#pragma unroll
            for (int kc = 0; kc < 2; ++kc) {
                const int q = wave * 32 + t2 * 16 + l15;
                aP[t2][kc] = *(const short8*)&Ps[q * PS_LD + kc * 32 + quad * 8];
            }
#pragma unroll
        for (int nt = 0; nt < 4; ++nt)
#pragma unroll
            for (int kc = 0; kc < 2; ++kc) {
                const int d = nt * 16 + l15;
                const short8 bV = *(const short8*)&Vt[d * VT_LD + kc * 32 + quad * 8];
                O[0][nt] = MFMA16(aP[0][kc], bV, O[0][nt]);
                O[1][nt] = MFMA16(aP[1][kc], bV, O[1][nt]);
            }
    }

    // epilogue: O/l -> ctx bf16 [B,S,D]
#pragma unroll
    for (int t2 = 0; t2 < 2; ++t2)
#pragma unroll
        for (int r = 0; r < 4; ++r) {
            const float inv = 1.f / lst[t2][r];
            const int s = q0 + wave * 32 + t2 * 16 + quad * 4 + r;
            u16* dst = Cb + ((size_t)b * S_ + s) * D_ + h * HD_;
#pragma unroll
            for (int nt = 0; nt < 4; ++nt)
                dst[nt * 16 + l15] = f2bf(O[t2][nt][r] * inv);
        }
}

// ---------------------------------------------------------------------------
extern "C" void kernel_launch(void* const* d_in, const int* in_sizes, int n_in,
                              void* d_out, int out_size, void* d_ws, size_t ws_size,
                              hipStream_t stream) {
    const float* X    = (const float*)d_in[0];
    const float* mask = (const float*)d_in[1];
    const float* pb   = (const float*)d_in[2];
    const float* Wq   = (const float*)d_in[3];
    const float* bq   = (const float*)d_in[4];
    const float* Wk   = (const float*)d_in[5];
    const float* bk   = (const float*)d_in[6];
    const float* Wv   = (const float*)d_in[7];
    const float* bv   = (const float*)d_in[8];
    const float* Wo   = (const float*)d_in[9];
    const float* bo   = (const float*)d_in[10];
    float* out = (float*)d_out;

    // workspace layout (bf16 elements): 48 MB total
    u16* Xb  = (u16*)d_ws;               // [4096,1024]        8 MB
    u16* Wtq = Xb  + (size_t)M_ * D_;    // [1024,1024] x4     2 MB each
    u16* Wtk = Wtq + (size_t)D_ * D_;
    u16* Wtv = Wtk + (size_t)D_ * D_;
    u16* Wto = Wtv + (size_t)D_ * D_;
    u16* Qw  = Wto + (size_t)D_ * D_;    // [B,H,S,HD]         8 MB each
    u16* Kw  = Qw  + (size_t)M_ * D_;
    u16* Vw  = Kw  + (size_t)M_ * D_;
    u16* Cb  = Vw  + (size_t)M_ * D_;    // [B,S,D]            8 MB

    cvt_bf16<<<(M_ * D_) / (256 * 4), 256, 0, stream>>>(X, Xb);
    wt_trans<<<dim3(32, 32, 4), 256, 0, stream>>>(Wq, Wk, Wv, Wo, Wtq, Wtk, Wtv, Wto);

    gemm_bt_bf16<<<dim3(M_ / 128, D_ / 128, 3), 256, 0, stream>>>(
        Xb, Wtq, Wtk, Wtv, bq, bk, bv, Qw, Kw, Vw, 1);

    attn_mfma<<<dim3((S_ / 128) * B_, H_), 256, 0, stream>>>(Qw, Kw, Vw, pb, mask, Cb);

    gemm_bt_bf16<<<dim3(M_ / 128, D_ / 128, 1), 256, 0, stream>>>(
        Cb, Wto, Wto, Wto, bo, bo, bo, out, out, out, 0);
}

// Round 3
// 513.639 us; speedup vs baseline: 3.7334x; 1.0306x over previous
//
#include <hip/hip_runtime.h>
#include <hip/hip_bf16.h>

#define B_  2
#define S_  2048
#define D_  1024
#define H_  16
#define HD_ 64
#define M_  (B_ * S_)   // 4096

typedef unsigned short u16;
typedef __attribute__((ext_vector_type(8))) short short8;
typedef __attribute__((ext_vector_type(4))) float f32x4;

#define MFMA16(a, b, c) __builtin_amdgcn_mfma_f32_16x16x32_bf16(a, b, c, 0, 0, 0)

__device__ __forceinline__ u16 f2bf(float f) {
    union { float f; unsigned u; } v; v.f = f;
    unsigned r = v.u + 0x7FFFu + ((v.u >> 16) & 1u);  // RNE
    return (u16)(r >> 16);
}

__device__ __forceinline__ void gl_lds16(const void* g, void* lds) {
    __builtin_amdgcn_global_load_lds(
        (const __attribute__((address_space(1))) unsigned int*)g,
        (__attribute__((address_space(3))) unsigned int*)lds, 16, 0, 0);
}

// ---------------------------------------------------------------------------
// Pre-pass 1: fp32 -> bf16 (X)
// ---------------------------------------------------------------------------
__global__ __launch_bounds__(256) void cvt_bf16(const float* __restrict__ x,
                                                u16* __restrict__ y) {
    const int i = (blockIdx.x * 256 + threadIdx.x) * 4;
    const float4 v = *(const float4*)(x + i);
    ushort4 o;
    o.x = f2bf(v.x); o.y = f2bf(v.y); o.z = f2bf(v.z); o.w = f2bf(v.w);
    *(ushort4*)(y + i) = o;
}

// ---------------------------------------------------------------------------
// Pre-pass 2: W[K,N] fp32 -> Wt[N,K] bf16, 4 weights via blockIdx.z
// (q,k,v outputs laid out contiguously -> fused [3072,1024] weight)
// ---------------------------------------------------------------------------
__global__ __launch_bounds__(256) void wt_trans(
    const float* __restrict__ w0, const float* __restrict__ w1,
    const float* __restrict__ w2, const float* __restrict__ w3,
    u16* __restrict__ t0, u16* __restrict__ t1,
    u16* __restrict__ t2, u16* __restrict__ t3) {
    const float* W; u16* T;
    switch (blockIdx.z) {
        case 0: W = w0; T = t0; break;
        case 1: W = w1; T = t1; break;
        case 2: W = w2; T = t2; break;
        default: W = w3; T = t3; break;
    }
    __shared__ float t[32][33];
    const int tid = threadIdx.x;
    const int kt = blockIdx.x, nt = blockIdx.y;
    const int r = tid >> 3, c4 = (tid & 7) * 4;
    const float4 v = *(const float4*)&W[(size_t)(kt * 32 + r) * D_ + nt * 32 + c4];
    t[c4 + 0][r] = v.x; t[c4 + 1][r] = v.y; t[c4 + 2][r] = v.z; t[c4 + 3][r] = v.w;
    __syncthreads();
    ushort4 o;
    o.x = f2bf(t[r][c4 + 0]); o.y = f2bf(t[r][c4 + 1]);
    o.z = f2bf(t[r][c4 + 2]); o.w = f2bf(t[r][c4 + 3]);
    *(ushort4*)&T[(size_t)(nt * 32 + r) * D_ + kt * 32 + c4] = o;
}

// ---------------------------------------------------------------------------
// Pre-pass 3: V [B,H,S,HD] bf16 -> VT [B,H,HD,S] bf16 (64x64 LDS tiles)
// ---------------------------------------------------------------------------
__global__ __launch_bounds__(256) void v_trans(const u16* __restrict__ V,
                                               u16* __restrict__ VT) {
    __shared__ u16 t[64][72];
    const int bh = blockIdx.x, s0 = blockIdx.y * 64;
    const int tid = threadIdx.x;
    const int ss = tid >> 2, cq = tid & 3;
    const u16* src = V + ((size_t)bh * S_ + s0 + ss) * HD_ + cq * 16;
    u16 buf[16];
    *(uint4*)&buf[0] = *(const uint4*)&src[0];
    *(uint4*)&buf[8] = *(const uint4*)&src[8];
#pragma unroll
    for (int j = 0; j < 16; ++j) t[cq * 16 + j][ss] = buf[j];
    __syncthreads();
    const int dd = tid >> 2;
    u16 ob[16];
#pragma unroll
    for (int j = 0; j < 16; ++j) ob[j] = t[dd][cq * 16 + j];
    u16* dst = VT + ((size_t)bh * HD_ + dd) * S_ + s0 + cq * 16;
    *(uint4*)&dst[0] = *(uint4*)&ob[0];
    *(uint4*)&dst[8] = *(uint4*)&ob[8];
}

// ---------------------------------------------------------------------------
// bf16 MFMA GEMM (m97 pattern): C[M,N] = A[M,K] @ Bt[N,K]^T + bias
// 128x128 tile, BK=32, 256 thr = 2x2 waves, 4x4 16x16x32 frags per wave.
// mode 1: scatter bf16 to [B,H,S,HD], output/bias selected by n>>10 (fused QKV,
//         N=3072 via grid.y=24). mode 0: fp32 row-major [M,1024].
// ---------------------------------------------------------------------------
__global__ __launch_bounds__(256) void gemm_bt_bf16(
    const u16* __restrict__ A, const u16* __restrict__ Bt,
    const float* __restrict__ bi0, const float* __restrict__ bi1, const float* __restrict__ bi2,
    void* __restrict__ o0, void* __restrict__ o1, void* __restrict__ o2,
    int mode) {
    __shared__ __align__(16) char smem[16384];   // As 8K | Bs 8K

    const int tid = threadIdx.x;
    const int wave = tid >> 6, lane = tid & 63;
    const int quad = lane >> 4, l15 = lane & 15;
    const int wm = wave >> 1, wn = wave & 1;
    const int bm = blockIdx.x * 128, bn = blockIdx.y * 128;

    const int sel = bn >> 10;
    const float* bias = (sel == 0) ? bi0 : (sel == 1) ? bi1 : bi2;
    void* outp = (sel == 0) ? o0 : (sel == 1) ? o1 : o2;

    f32x4 acc[4][4];
#pragma unroll
    for (int i = 0; i < 4; ++i)
#pragma unroll
        for (int j = 0; j < 4; ++j) acc[i][j] = (f32x4)0.f;

    for (int k0 = 0; k0 < D_; k0 += 32) {
        __syncthreads();
#pragma unroll
        for (int i = 0; i < 2; ++i) {
            const int c = (wave * 2 + i) * 64 + lane;   // 16B chunk id 0..511
            const int row = c >> 2, e = c & 3;
            gl_lds16(A  + (size_t)(bm + row) * D_ + k0 + e * 8,
                     smem + (wave * 2 + i) * 1024);
            gl_lds16(Bt + (size_t)(bn + row) * D_ + k0 + e * 8,
                     smem + 8192 + (wave * 2 + i) * 1024);
        }
        __syncthreads();

        short8 aF[4], bF[4];
#pragma unroll
        for (int mt = 0; mt < 4; ++mt)
            aF[mt] = *(const short8*)(smem + ((wm * 64 + mt * 16 + l15) * 32 + quad * 8) * 2);
#pragma unroll
        for (int nt = 0; nt < 4; ++nt)
            bF[nt] = *(const short8*)(smem + 8192 + ((wn * 64 + nt * 16 + l15) * 32 + quad * 8) * 2);
#pragma unroll
        for (int mt = 0; mt < 4; ++mt)
#pragma unroll
            for (int nt = 0; nt < 4; ++nt)
                acc[mt][nt] = MFMA16(aF[mt], bF[nt], acc[mt][nt]);
    }

    float bv[4];
#pragma unroll
    for (int nt = 0; nt < 4; ++nt)
        bv[nt] = bias[(bn & 1023) + wn * 64 + nt * 16 + l15];

    if (mode == 1) {
        u16* ob = (u16*)outp;
#pragma unroll
        for (int mt = 0; mt < 4; ++mt)
#pragma unroll
            for (int nt = 0; nt < 4; ++nt)
#pragma unroll
                for (int r = 0; r < 4; ++r) {
                    const int m = bm + wm * 64 + mt * 16 + quad * 4 + r;
                    const int n = (bn & 1023) + wn * 64 + nt * 16 + l15;
                    const int bb = m >> 11, ss = m & (S_ - 1);
                    const int hh = n >> 6,  dd = n & (HD_ - 1);
                    ob[(((size_t)bb * H_ + hh) * S_ + ss) * HD_ + dd] =
                        f2bf(acc[mt][nt][r] + bv[nt]);
                }
    } else {
        float* of = (float*)outp;
#pragma unroll
        for (int mt = 0; mt < 4; ++mt)
#pragma unroll
            for (int nt = 0; nt < 4; ++nt)
#pragma unroll
                for (int r = 0; r < 4; ++r) {
                    const int m = bm + wm * 64 + mt * 16 + quad * 4 + r;
                    const int n = bn + wn * 64 + nt * 16 + l15;
                    of[(size_t)m * D_ + n] = acc[mt][nt][r] + bv[nt];
                }
    }
}

// ---------------------------------------------------------------------------
// MFMA flash attention, TQ=64. Block = 256 thr (4 waves x 16 q-rows),
// k-tiles of 64. Q/K/VT staged via global_load_lds with XOR chunk swizzle
// (VT pre-transposed globally -> pure DMA, no in-kernel transpose).
// Q fragments hoisted out of the k-loop. LDS 33.8 KB -> 4 blocks/CU.
// ---------------------------------------------------------------------------
#define AQ_OFF  0       // Q  64x64 bf16 swizzled: 8192
#define AK_OFF  8192    // K  64x64 bf16 swizzled: 8192
#define AV_OFF  16384   // VT 64d x 64k bf16 swizzled: 8192
#define APS_OFF 24576   // Ps [64][72] bf16: 9216  -> total 33792
#define PS_LD 72

__global__ __launch_bounds__(256, 4) void attn_mfma(
    const u16* __restrict__ Qg, const u16* __restrict__ Kg, const u16* __restrict__ VTg,
    const float* __restrict__ pb, const float* __restrict__ mask,
    u16* __restrict__ Cb) {
    __shared__ __align__(16) char smem[33792];
    u16* Ps = (u16*)(smem + APS_OFF);

    const int tid = threadIdx.x;
    const int wave = tid >> 6, lane = tid & 63;
    const int quad = lane >> 4, l15 = lane & 15;

    const int b = blockIdx.x & 1, qblk = blockIdx.x >> 1;
    const int h = blockIdx.y;
    const int q0 = qblk * 64;

    const size_t bh = (size_t)b * H_ + h;
    const u16* Qb  = Qg  + bh * (S_ * HD_);
    const u16* Kb  = Kg  + bh * (S_ * HD_);
    const u16* VTb = VTg + bh * (HD_ * S_);   // [HD][S]

    // stage Q tile 64x64 swizzled: chunk (q,e) holds global d-chunk e^(q&7)
#pragma unroll
    for (int i = 0; i < 2; ++i) {
        const int c = (wave * 2 + i) * 64 + lane;  // 0..511
        const int q = c >> 3, e = c & 7, dc = e ^ (q & 7);
        gl_lds16(Qb + (size_t)(q0 + q) * HD_ + dc * 8,
                 smem + AQ_OFF + (wave * 2 + i) * 1024);
    }
    __syncthreads();

    // hoisted Q fragments (k-tile invariant)
    short8 aQ[2];
#pragma unroll
    for (int kc = 0; kc < 2; ++kc) {
        const int q = wave * 16 + l15;
        const int dc = kc * 4 + quad;
        aQ[kc] = *(const short8*)(smem + AQ_OFF + (q * 8 + (dc ^ (q & 7))) * 16);
    }

    f32x4 O[4];
    float mst[4], lst[4];
#pragma unroll
    for (int nt = 0; nt < 4; ++nt) O[nt] = (f32x4)0.f;
#pragma unroll
    for (int r = 0; r < 4; ++r) { mst[r] = -1e30f; lst[r] = 0.f; }

    for (int kt = 0; kt < S_ / 64; ++kt) {
        const int k0 = kt * 64;
        __syncthreads();   // prior consumers of K/VT done (no-op effect at kt=0)

        // stage K tile 64x64 swizzled + VT tile [64 d][64 k] swizzled (pure DMA)
#pragma unroll
        for (int i = 0; i < 2; ++i) {
            const int c = (wave * 2 + i) * 64 + lane;  // 0..511
            const int q = c >> 3, e = c & 7, dc = e ^ (q & 7);
            gl_lds16(Kb + (size_t)(k0 + q) * HD_ + dc * 8,
                     smem + AK_OFF + (wave * 2 + i) * 1024);
            gl_lds16(VTb + (size_t)q * S_ + k0 + dc * 8,
                     smem + AV_OFF + (wave * 2 + i) * 1024);
        }

        // bias + mask into C-layout registers (overlaps DMA)
        float mk[4], pbv[4][4];
#pragma unroll
        for (int nt = 0; nt < 4; ++nt) mk[nt] = mask[b * S_ + k0 + nt * 16 + l15];
#pragma unroll
        for (int r = 0; r < 4; ++r) {
            const int qg = q0 + wave * 16 + quad * 4 + r;
            const float* rowp = pb + ((size_t)h * S_ + qg) * S_ + k0;
#pragma unroll
            for (int nt = 0; nt < 4; ++nt) pbv[r][nt] = rowp[nt * 16 + l15];
        }
        __syncthreads();   // staging visible

        // ---- QK^T ----
        f32x4 sc[4];
#pragma unroll
        for (int nt = 0; nt < 4; ++nt) sc[nt] = (f32x4)0.f;
#pragma unroll
        for (int nt = 0; nt < 4; ++nt)
#pragma unroll
            for (int kc = 0; kc < 2; ++kc) {
                const int kk = nt * 16 + l15;
                const int dc = kc * 4 + quad;
                const short8 bK = *(const short8*)(smem + AK_OFF + (kk * 8 + (dc ^ (kk & 7))) * 16);
                sc[nt] = MFMA16(aQ[kc], bK, sc[nt]);
            }

        // ---- online softmax (rows = quad*4+r), P to wave-private LDS ----
#pragma unroll
        for (int r = 0; r < 4; ++r) {
            float s0 = fmaf(sc[0][r], 0.125f, pbv[r][0] + mk[0]);
            float s1 = fmaf(sc[1][r], 0.125f, pbv[r][1] + mk[1]);
            float s2 = fmaf(sc[2][r], 0.125f, pbv[r][2] + mk[2]);
            float s3 = fmaf(sc[3][r], 0.125f, pbv[r][3] + mk[3]);
            float rmax = fmaxf(fmaxf(s0, s1), fmaxf(s2, s3));
#pragma unroll
            for (int off = 1; off < 16; off <<= 1)
                rmax = fmaxf(rmax, __shfl_xor(rmax, off, 64));
            const float mo = mst[r];
            const float mn = fmaxf(mo, rmax);
            const float al = __expf(mo - mn);
            const float p0 = __expf(s0 - mn), p1 = __expf(s1 - mn);
            const float p2 = __expf(s2 - mn), p3 = __expf(s3 - mn);
            float ls = (p0 + p1) + (p2 + p3);
#pragma unroll
            for (int off = 1; off < 16; off <<= 1)
                ls += __shfl_xor(ls, off, 64);
            mst[r] = mn;
            lst[r] = fmaf(lst[r], al, ls);
            const int qr = wave * 16 + quad * 4 + r;
            Ps[qr * PS_LD +  0 + l15] = f2bf(p0);
            Ps[qr * PS_LD + 16 + l15] = f2bf(p1);
            Ps[qr * PS_LD + 32 + l15] = f2bf(p2);
            Ps[qr * PS_LD + 48 + l15] = f2bf(p3);
            O[0][r] *= al; O[1][r] *= al; O[2][r] *= al; O[3][r] *= al;
        }

        // ---- PV (A from wave-private Ps: in-wave DS ordering, no barrier) ----
        short8 aP[2];
#pragma unroll
        for (int kc = 0; kc < 2; ++kc) {
            const int q = wave * 16 + l15;
            aP[kc] = *(const short8*)&Ps[q * PS_LD + kc * 32 + quad * 8];
        }
#pragma unroll
        for (int nt = 0; nt < 4; ++nt)
#pragma unroll
            for (int kc = 0; kc < 2; ++kc) {
                const int d = nt * 16 + l15;
                const int dc = kc * 4 + quad;
                const short8 bV = *(const short8*)(smem + AV_OFF + (d * 8 + (dc ^ (d & 7))) * 16);
                O[nt] = MFMA16(aP[kc], bV, O[nt]);
            }
    }

    // epilogue: O/l -> ctx bf16 [B,S,D]
#pragma unroll
    for (int r = 0; r < 4; ++r) {
        const float inv = 1.f / lst[r];
        const int s = q0 + wave * 16 + quad * 4 + r;
        u16* dst = Cb + ((size_t)b * S_ + s) * D_ + h * HD_;
#pragma unroll
        for (int nt = 0; nt < 4; ++nt)
            dst[nt * 16 + l15] = f2bf(O[nt][r] * inv);
    }
}

// ---------------------------------------------------------------------------
extern "C" void kernel_launch(void* const* d_in, const int* in_sizes, int n_in,
                              void* d_out, int out_size, void* d_ws, size_t ws_size,
                              hipStream_t stream) {
    const float* X    = (const float*)d_in[0];
    const float* mask = (const float*)d_in[1];
    const float* pb   = (const float*)d_in[2];
    const float* Wq   = (const float*)d_in[3];
    const float* bq   = (const float*)d_in[4];
    const float* Wk   = (const float*)d_in[5];
    const float* bk   = (const float*)d_in[6];
    const float* Wv   = (const float*)d_in[7];
    const float* bv   = (const float*)d_in[8];
    const float* Wo   = (const float*)d_in[9];
    const float* bo   = (const float*)d_in[10];
    float* out = (float*)d_out;

    // workspace (bf16 elems): 56 MB total (ws >= 64 MB per round-1 usage)
    u16* Xb    = (u16*)d_ws;                     // [4096,1024]       8 MB
    u16* WtQKV = Xb    + (size_t)M_ * D_;        // [3072,1024]       6 MB
    u16* Wto   = WtQKV + (size_t)3 * D_ * D_;    // [1024,1024]       2 MB
    u16* Qw    = Wto   + (size_t)D_ * D_;        // [B,H,S,HD]        8 MB
    u16* Kw    = Qw    + (size_t)M_ * D_;        //                   8 MB
    u16* Vw    = Kw    + (size_t)M_ * D_;        //                   8 MB
    u16* Cb    = Vw    + (size_t)M_ * D_;        // [B,S,D]           8 MB
    u16* VTw   = Cb    + (size_t)M_ * D_;        // [B,H,HD,S]        8 MB

    cvt_bf16<<<(M_ * D_) / (256 * 4), 256, 0, stream>>>(X, Xb);
    wt_trans<<<dim3(32, 32, 4), 256, 0, stream>>>(
        Wq, Wk, Wv, Wo, WtQKV, WtQKV + (size_t)D_ * D_, WtQKV + (size_t)2 * D_ * D_, Wto);

    // fused QKV: N = 3072
    gemm_bt_bf16<<<dim3(M_ / 128, 3 * D_ / 128), 256, 0, stream>>>(
        Xb, WtQKV, bq, bk, bv, Qw, Kw, Vw, 1);

    v_trans<<<dim3(B_ * H_, S_ / 64), 256, 0, stream>>>(Vw, VTw);

    attn_mfma<<<dim3((S_ / 64) * B_, H_), 256, 0, stream>>>(Qw, Kw, VTw, pb, mask, Cb);

    gemm_bt_bf16<<<dim3(M_ / 128, D_ / 128), 256, 0, stream>>>(
        Cb, Wto, bo, bo, bo, out, out, out, 0);
}

// Round 4
// 508.208 us; speedup vs baseline: 3.7733x; 1.0107x over previous
//
#include <hip/hip_runtime.h>
#include <hip/hip_bf16.h>

#define B_  2
#define S_  2048
#define D_  1024
#define H_  16
#define HD_ 64
#define M_  (B_ * S_)   // 4096

typedef unsigned short u16;
typedef __attribute__((ext_vector_type(8))) short short8;
typedef __attribute__((ext_vector_type(4))) float f32x4;

#define MFMA16(a, b, c) __builtin_amdgcn_mfma_f32_16x16x32_bf16(a, b, c, 0, 0, 0)

__device__ __forceinline__ u16 f2bf(float f) {
    union { float f; unsigned u; } v; v.f = f;
    unsigned r = v.u + 0x7FFFu + ((v.u >> 16) & 1u);  // RNE
    return (u16)(r >> 16);
}

__device__ __forceinline__ void gl_lds16(const void* g, void* lds) {
    __builtin_amdgcn_global_load_lds(
        (const __attribute__((address_space(1))) unsigned int*)g,
        (__attribute__((address_space(3))) unsigned int*)lds, 16, 0, 0);
}

// ---------------------------------------------------------------------------
// Pre-pass 1: fp32 -> bf16 (X)
// ---------------------------------------------------------------------------
__global__ __launch_bounds__(256) void cvt_bf16(const float* __restrict__ x,
                                                u16* __restrict__ y) {
    const int i = (blockIdx.x * 256 + threadIdx.x) * 4;
    const float4 v = *(const float4*)(x + i);
    ushort4 o;
    o.x = f2bf(v.x); o.y = f2bf(v.y); o.z = f2bf(v.z); o.w = f2bf(v.w);
    *(ushort4*)(y + i) = o;
}

// ---------------------------------------------------------------------------
// Pre-pass 2: W[K,N] fp32 -> Wt[N,K] bf16, 4 weights via blockIdx.z
// ---------------------------------------------------------------------------
__global__ __launch_bounds__(256) void wt_trans(
    const float* __restrict__ w0, const float* __restrict__ w1,
    const float* __restrict__ w2, const float* __restrict__ w3,
    u16* __restrict__ t0, u16* __restrict__ t1,
    u16* __restrict__ t2, u16* __restrict__ t3) {
    const float* W; u16* T;
    switch (blockIdx.z) {
        case 0: W = w0; T = t0; break;
        case 1: W = w1; T = t1; break;
        case 2: W = w2; T = t2; break;
        default: W = w3; T = t3; break;
    }
    __shared__ float t[32][33];
    const int tid = threadIdx.x;
    const int kt = blockIdx.x, nt = blockIdx.y;
    const int r = tid >> 3, c4 = (tid & 7) * 4;
    const float4 v = *(const float4*)&W[(size_t)(kt * 32 + r) * D_ + nt * 32 + c4];
    t[c4 + 0][r] = v.x; t[c4 + 1][r] = v.y; t[c4 + 2][r] = v.z; t[c4 + 3][r] = v.w;
    __syncthreads();
    ushort4 o;
    o.x = f2bf(t[r][c4 + 0]); o.y = f2bf(t[r][c4 + 1]);
    o.z = f2bf(t[r][c4 + 2]); o.w = f2bf(t[r][c4 + 3]);
    *(ushort4*)&T[(size_t)(nt * 32 + r) * D_ + kt * 32 + c4] = o;
}

// ---------------------------------------------------------------------------
// Pre-pass 3: V [B,H,S,HD] bf16 -> VT [B,H,HD,S] bf16 (64x64 LDS tiles)
// ---------------------------------------------------------------------------
__global__ __launch_bounds__(256) void v_trans(const u16* __restrict__ V,
                                               u16* __restrict__ VT) {
    __shared__ u16 t[64][72];
    const int bh = blockIdx.x, s0 = blockIdx.y * 64;
    const int tid = threadIdx.x;
    const int ss = tid >> 2, cq = tid & 3;
    const u16* src = V + ((size_t)bh * S_ + s0 + ss) * HD_ + cq * 16;
    u16 buf[16];
    *(uint4*)&buf[0] = *(const uint4*)&src[0];
    *(uint4*)&buf[8] = *(const uint4*)&src[8];
#pragma unroll
    for (int j = 0; j < 16; ++j) t[cq * 16 + j][ss] = buf[j];
    __syncthreads();
    const int dd = tid >> 2;
    u16 ob[16];
#pragma unroll
    for (int j = 0; j < 16; ++j) ob[j] = t[dd][cq * 16 + j];
    u16* dst = VT + ((size_t)bh * HD_ + dd) * S_ + s0 + cq * 16;
    *(uint4*)&dst[0] = *(uint4*)&ob[0];
    *(uint4*)&dst[8] = *(uint4*)&ob[8];
}

// ---------------------------------------------------------------------------
// bf16 MFMA GEMM, double-buffered single-barrier K-loop.
// C[M,N] = A[M,K] @ Bt[N,K]^T + bias. 128x128 tile, BK=32, 256 thr (2x2 waves).
// LDS: A0 | A1 | B0 | B1 (8 KB each) = 32 KB.
// mode 1: scatter bf16 to [B,H,S,HD], out/bias by n>>10 (fused QKV, grid.y=24).
// mode 0: fp32 row-major [M,1024].
// ---------------------------------------------------------------------------
__global__ __launch_bounds__(256, 3) void gemm_bt_bf16(
    const u16* __restrict__ A, const u16* __restrict__ Bt,
    const float* __restrict__ bi0, const float* __restrict__ bi1, const float* __restrict__ bi2,
    void* __restrict__ o0, void* __restrict__ o1, void* __restrict__ o2,
    int mode) {
    __shared__ __align__(16) char smem[32768];

    const int tid = threadIdx.x;
    const int wave = tid >> 6, lane = tid & 63;
    const int quad = lane >> 4, l15 = lane & 15;
    const int wm = wave >> 1, wn = wave & 1;
    const int bm = blockIdx.x * 128, bn = blockIdx.y * 128;

    const int sel = bn >> 10;
    const float* bias = (sel == 0) ? bi0 : (sel == 1) ? bi1 : bi2;
    void* outp = (sel == 0) ? o0 : (sel == 1) ? o1 : o2;

    f32x4 acc[4][4];
#pragma unroll
    for (int i = 0; i < 4; ++i)
#pragma unroll
        for (int j = 0; j < 4; ++j) acc[i][j] = (f32x4)0.f;

    // chunk assignment for staging: c in 0..511, row=c>>2, e=c&3
    const int c0 = wave * 128 + lane;          // base chunk (i=0); i adds 64
    // prologue: stage k0=0 into buf0
#pragma unroll
    for (int i = 0; i < 2; ++i) {
        const int c = c0 + i * 64;
        const int row = c >> 2, e = c & 3;
        gl_lds16(A  + (size_t)(bm + row) * D_ + e * 8,
                 smem + (wave * 2 + i) * 1024);
        gl_lds16(Bt + (size_t)(bn + row) * D_ + e * 8,
                 smem + 16384 + (wave * 2 + i) * 1024);
    }
    __syncthreads();

    for (int it = 0; it < 32; ++it) {
        const int cur = it & 1;
        // stage next tile into the other buffer (DMA overlaps compute below)
        if (it < 31) {
            const int k0n = (it + 1) * 32;
            const int nb = cur ^ 1;
#pragma unroll
            for (int i = 0; i < 2; ++i) {
                const int c = c0 + i * 64;
                const int row = c >> 2, e = c & 3;
                gl_lds16(A  + (size_t)(bm + row) * D_ + k0n + e * 8,
                         smem + nb * 8192 + (wave * 2 + i) * 1024);
                gl_lds16(Bt + (size_t)(bn + row) * D_ + k0n + e * 8,
                         smem + 16384 + nb * 8192 + (wave * 2 + i) * 1024);
            }
        }

        short8 aF[4], bF[4];
#pragma unroll
        for (int mt = 0; mt < 4; ++mt)
            aF[mt] = *(const short8*)(smem + cur * 8192 +
                     ((wm * 64 + mt * 16 + l15) * 32 + quad * 8) * 2);
#pragma unroll
        for (int nt = 0; nt < 4; ++nt)
            bF[nt] = *(const short8*)(smem + 16384 + cur * 8192 +
                     ((wn * 64 + nt * 16 + l15) * 32 + quad * 8) * 2);
#pragma unroll
        for (int mt = 0; mt < 4; ++mt)
#pragma unroll
            for (int nt = 0; nt < 4; ++nt)
                acc[mt][nt] = MFMA16(aF[mt], bF[nt], acc[mt][nt]);

        __syncthreads();   // next-tile DMA complete + all waves done with cur
    }

    float bv[4];
#pragma unroll
    for (int nt = 0; nt < 4; ++nt)
        bv[nt] = bias[(bn & 1023) + wn * 64 + nt * 16 + l15];

    if (mode == 1) {
        u16* ob = (u16*)outp;
#pragma unroll
        for (int mt = 0; mt < 4; ++mt)
#pragma unroll
            for (int nt = 0; nt < 4; ++nt)
#pragma unroll
                for (int r = 0; r < 4; ++r) {
                    const int m = bm + wm * 64 + mt * 16 + quad * 4 + r;
                    const int n = (bn & 1023) + wn * 64 + nt * 16 + l15;
                    const int bb = m >> 11, ss = m & (S_ - 1);
                    const int hh = n >> 6,  dd = n & (HD_ - 1);
                    ob[(((size_t)bb * H_ + hh) * S_ + ss) * HD_ + dd] =
                        f2bf(acc[mt][nt][r] + bv[nt]);
                }
    } else {
        float* of = (float*)outp;
#pragma unroll
        for (int mt = 0; mt < 4; ++mt)
#pragma unroll
            for (int nt = 0; nt < 4; ++nt)
#pragma unroll
                for (int r = 0; r < 4; ++r) {
                    const int m = bm + wm * 64 + mt * 16 + quad * 4 + r;
                    const int n = bn + wn * 64 + nt * 16 + l15;
                    of[(size_t)m * D_ + n] = acc[mt][nt][r] + bv[nt];
                }
    }
}

// ---------------------------------------------------------------------------
// MFMA flash attention, TQ=64, double-buffered K/V, no-max softmax.
// Block = 256 thr (4 waves x 16 q-rows). Q staged once (region reused for Ps
// after aQ register hoist — all Q/Ps rows are wave-private, no barrier needed).
// Ps layout: kchunk-major [8 kchunks][64 q][8 u16] -> conflict-free aP reads.
// LDS = 8K(Q/Ps) + 2x8K(K) + 2x8K(V) = 40960 B -> 4 blocks/CU.
// ---------------------------------------------------------------------------
#define AQP_OFF 0
#define AK_OFF  8192    // + 8192*buf
#define AV_OFF  24576   // + 8192*buf

__global__ __launch_bounds__(256, 4) void attn_mfma(
    const u16* __restrict__ Qg, const u16* __restrict__ Kg, const u16* __restrict__ VTg,
    const float* __restrict__ pb, const float* __restrict__ mask,
    u16* __restrict__ Cb) {
    __shared__ __align__(16) char smem[40960];
    u16* PsU = (u16*)(smem + AQP_OFF);

    const int tid = threadIdx.x;
    const int wave = tid >> 6, lane = tid & 63;
    const int quad = lane >> 4, l15 = lane & 15;

    const int b = blockIdx.x & 1, qblk = blockIdx.x >> 1;
    const int h = blockIdx.y;
    const int q0 = qblk * 64;

    const size_t bh = (size_t)b * H_ + h;
    const u16* Qb  = Qg  + bh * (S_ * HD_);
    const u16* Kb  = Kg  + bh * (S_ * HD_);
    const u16* VTb = VTg + bh * (HD_ * S_);   // [HD][S]

    // ---- prologue: stage Q + K/V tile 0 (buf 0) ----
#pragma unroll
    for (int i = 0; i < 2; ++i) {
        const int c = (wave * 2 + i) * 64 + lane;  // 0..511
        const int row = c >> 3, e = c & 7, dc = e ^ (row & 7);
        gl_lds16(Qb + (size_t)(q0 + row) * HD_ + dc * 8,
                 smem + AQP_OFF + (wave * 2 + i) * 1024);
        gl_lds16(Kb + (size_t)row * HD_ + dc * 8,
                 smem + AK_OFF + (wave * 2 + i) * 1024);
        gl_lds16(VTb + (size_t)row * S_ + dc * 8,
                 smem + AV_OFF + (wave * 2 + i) * 1024);
    }
    __syncthreads();

    // hoist Q fragments (own-wave rows only)
    short8 aQ[2];
#pragma unroll
    for (int kc = 0; kc < 2; ++kc) {
        const int q = wave * 16 + l15;
        const int dc = kc * 4 + quad;
        aQ[kc] = *(const short8*)(smem + AQP_OFF + (q * 8 + (dc ^ (q & 7))) * 16);
    }

    // Ps addressing (kchunk-major): write base for this thread
    u16* Pw = PsU + (l15 >> 3) * 512 + (wave * 16 + quad * 4) * 8 + (l15 & 7);

    f32x4 O[4];
    float lst[4];
#pragma unroll
    for (int nt = 0; nt < 4; ++nt) O[nt] = (f32x4)0.f;
#pragma unroll
    for (int r = 0; r < 4; ++r) lst[r] = 0.f;

    for (int kt = 0; kt < S_ / 64; ++kt) {
        const int k0 = kt * 64;
        const int cur = kt & 1;

        // stage next K/V tile into the other buffer (overlaps compute)
        if (kt < S_ / 64 - 1) {
            const int nb = cur ^ 1;
            const int k0n = k0 + 64;
#pragma unroll
            for (int i = 0; i < 2; ++i) {
                const int c = (wave * 2 + i) * 64 + lane;
                const int row = c >> 3, e = c & 7, dc = e ^ (row & 7);
                gl_lds16(Kb + (size_t)(k0n + row) * HD_ + dc * 8,
                         smem + AK_OFF + nb * 8192 + (wave * 2 + i) * 1024);
                gl_lds16(VTb + (size_t)row * S_ + k0n + dc * 8,
                         smem + AV_OFF + nb * 8192 + (wave * 2 + i) * 1024);
            }
        }

        // bias + mask into C-layout registers (VMEM overlaps MFMA)
        float mk[4], pbv[4][4];
#pragma unroll
        for (int nt = 0; nt < 4; ++nt) mk[nt] = mask[b * S_ + k0 + nt * 16 + l15];
#pragma unroll
        for (int r = 0; r < 4; ++r) {
            const int qg = q0 + wave * 16 + quad * 4 + r;
            const float* rowp = pb + ((size_t)h * S_ + qg) * S_ + k0;
#pragma unroll
            for (int nt = 0; nt < 4; ++nt) pbv[r][nt] = rowp[nt * 16 + l15];
        }

        // ---- QK^T on buf[cur] ----
        f32x4 sc[4];
#pragma unroll
        for (int nt = 0; nt < 4; ++nt) sc[nt] = (f32x4)0.f;
#pragma unroll
        for (int nt = 0; nt < 4; ++nt)
#pragma unroll
            for (int kc = 0; kc < 2; ++kc) {
                const int kk = nt * 16 + l15;
                const int dc = kc * 4 + quad;
                const short8 bK = *(const short8*)(smem + AK_OFF + cur * 8192 +
                                   (kk * 8 + (dc ^ (kk & 7))) * 16);
                sc[nt] = MFMA16(aQ[kc], bK, sc[nt]);
            }

        // ---- no-max softmax: p = exp(s), per-lane partial row sums ----
#pragma unroll
        for (int r = 0; r < 4; ++r) {
            const float s0 = fmaf(sc[0][r], 0.125f, pbv[r][0] + mk[0]);
            const float s1 = fmaf(sc[1][r], 0.125f, pbv[r][1] + mk[1]);
            const float s2 = fmaf(sc[2][r], 0.125f, pbv[r][2] + mk[2]);
            const float s3 = fmaf(sc[3][r], 0.125f, pbv[r][3] + mk[3]);
            const float p0 = __expf(s0), p1 = __expf(s1);
            const float p2 = __expf(s2), p3 = __expf(s3);
            lst[r] += (p0 + p1) + (p2 + p3);
            Pw[0 * 1024 + r * 8] = f2bf(p0);
            Pw[1 * 1024 + r * 8] = f2bf(p1);
            Pw[2 * 1024 + r * 8] = f2bf(p2);
            Pw[3 * 1024 + r * 8] = f2bf(p3);
        }

        // ---- PV on buf[cur] (Ps is wave-private; in-wave DS ordering) ----
        short8 aP[2];
#pragma unroll
        for (int kc = 0; kc < 2; ++kc)
            aP[kc] = *(const short8*)(PsU + (kc * 4 + quad) * 512 + (wave * 16 + l15) * 8);
#pragma unroll
        for (int nt = 0; nt < 4; ++nt)
#pragma unroll
            for (int kc = 0; kc < 2; ++kc) {
                const int d = nt * 16 + l15;
                const int dc = kc * 4 + quad;
                const short8 bV = *(const short8*)(smem + AV_OFF + cur * 8192 +
                                   (d * 8 + (dc ^ (d & 7))) * 16);
                O[nt] = MFMA16(aP[kc], bV, O[nt]);
            }

        __syncthreads();   // next-tile DMA complete + all waves done with cur
    }

    // ---- epilogue: reduce l across the 16 col-lanes, write ctx bf16 ----
#pragma unroll
    for (int r = 0; r < 4; ++r) {
#pragma unroll
        for (int off = 1; off < 16; off <<= 1)
            lst[r] += __shfl_xor(lst[r], off, 64);
        const float inv = 1.f / lst[r];
        const int s = q0 + wave * 16 + quad * 4 + r;
        u16* dst = Cb + ((size_t)b * S_ + s) * D_ + h * HD_;
#pragma unroll
        for (int nt = 0; nt < 4; ++nt)
            dst[nt * 16 + l15] = f2bf(O[nt][r] * inv);
    }
}

// ---------------------------------------------------------------------------
extern "C" void kernel_launch(void* const* d_in, const int* in_sizes, int n_in,
                              void* d_out, int out_size, void* d_ws, size_t ws_size,
                              hipStream_t stream) {
    const float* X    = (const float*)d_in[0];
    const float* mask = (const float*)d_in[1];
    const float* pb   = (const float*)d_in[2];
    const float* Wq   = (const float*)d_in[3];
    const float* bq   = (const float*)d_in[4];
    const float* Wk   = (const float*)d_in[5];
    const float* bk   = (const float*)d_in[6];
    const float* Wv   = (const float*)d_in[7];
    const float* bv   = (const float*)d_in[8];
    const float* Wo   = (const float*)d_in[9];
    const float* bo   = (const float*)d_in[10];
    float* out = (float*)d_out;

    // workspace (bf16 elems): 56 MB total
    u16* Xb    = (u16*)d_ws;                     // [4096,1024]       8 MB
    u16* WtQKV = Xb    + (size_t)M_ * D_;        // [3072,1024]       6 MB
    u16* Wto   = WtQKV + (size_t)3 * D_ * D_;    // [1024,1024]       2 MB
    u16* Qw    = Wto   + (size_t)D_ * D_;        // [B,H,S,HD]        8 MB
    u16* Kw    = Qw    + (size_t)M_ * D_;        //                   8 MB
    u16* Vw    = Kw    + (size_t)M_ * D_;        //                   8 MB
    u16* Cb    = Vw    + (size_t)M_ * D_;        // [B,S,D]           8 MB
    u16* VTw   = Cb    + (size_t)M_ * D_;        // [B,H,HD,S]        8 MB

    cvt_bf16<<<(M_ * D_) / (256 * 4), 256, 0, stream>>>(X, Xb);
    wt_trans<<<dim3(32, 32, 4), 256, 0, stream>>>(
        Wq, Wk, Wv, Wo, WtQKV, WtQKV + (size_t)D_ * D_, WtQKV + (size_t)2 * D_ * D_, Wto);

    // fused QKV: N = 3072
    gemm_bt_bf16<<<dim3(M_ / 128, 3 * D_ / 128), 256, 0, stream>>>(
        Xb, WtQKV, bq, bk, bv, Qw, Kw, Vw, 1);

    v_trans<<<dim3(B_ * H_, S_ / 64), 256, 0, stream>>>(Vw, VTw);

    attn_mfma<<<dim3((S_ / 64) * B_, H_), 256, 0, stream>>>(Qw, Kw, VTw, pb, mask, Cb);

    gemm_bt_bf16<<<dim3(M_ / 128, D_ / 128), 256, 0, stream>>>(
        Cb, Wto, bo, bo, bo, out, out, out, 0);
}